// Round 5
// baseline (137.471 us; speedup 1.0000x reference)
//
#include <hip/hip_runtime.h>
#include <hip/hip_fp16.h>

// Problem: inputs (8, 64, 16, 32, 32) fp32, embedding (1024, 64) fp32
#define THW    16384
#define NTOT   131072
#define KDIM   1024
#define CDIM   64
#define QELEMS 8388608          // 8*64*16*32*32
#define LOSS_OFF 8388608
#define IDX_OFF  8388610
#define BN     128              // queries per block (4 waves x 32 queries)

typedef _Float16 half8   __attribute__((ext_vector_type(8)));
typedef _Float16 half4_t __attribute__((ext_vector_type(4)));
typedef float    f32x4   __attribute__((ext_vector_type(4)));

// ---- prep: zero losses; split E into fp16 hi/lo (lo scaled 2^12) into ONE
// interleaved buffer Ef[tile][slot][lane][8], slots = {h.ch0, h.ch1, l.ch0,
// l.ch1}; tile = 4 KB, linear in the exact lane order vq_main's ds_reads use,
// so global_load_lds (wave-uniform base + lane*16) can stage it untouched.
// me2h[row] = -0.5*||e||^2 (seeds the hh MFMA chain directly).
__global__ __launch_bounds__(256) void vq_prep(const float* __restrict__ emb,
        _Float16* __restrict__ Ef, float* __restrict__ me2h,
        float* __restrict__ out) {
    const int t = threadIdx.x;
    if (blockIdx.x == 0 && t == 0) { out[LOSS_OFF] = 0.f; out[LOSS_OFF + 1] = 0.f; }
    const int ln   = t >> 4;
    const int g    = t & 15;
    const int tile = blockIdx.x;
    const int row  = tile * 16 + ln;
    const int c0   = g * 4;
    float4 v = *(const float4*)(emb + (size_t)row * CDIM + c0);
    const float xs[4] = {v.x, v.y, v.z, v.w};
    half4_t h, l;
    float s = 0.f;
    #pragma unroll
    for (int j = 0; j < 4; ++j) {
        const _Float16 hj = (_Float16)xs[j];
        const _Float16 lj = (_Float16)((xs[j] - (float)hj) * 4096.0f);
        h[j] = hj; l[j] = lj;
        s = fmaf(xs[j], xs[j], s);
    }
    const int ch = c0 >> 5;
    const int lq = (c0 & 31) >> 3;
    const int j0 = c0 & 7;
    const int fl = lq * 16 + ln;
    *(half4_t*)(Ef + (((size_t)tile * 4 + ch)     * 64 + fl) * 8 + j0) = h;
    *(half4_t*)(Ef + (((size_t)tile * 4 + 2 + ch) * 64 + fl) * 8 + j0) = l;
    #pragma unroll
    for (int off = 1; off < 16; off <<= 1) s += __shfl_xor(s, off, 64);
    if (g == 0) me2h[row] = -0.5f * s;
}

// ---- main: counted-vmcnt 3-buffer pipeline with 8 KB (2-tile) stages.
// Loop footprint 28.7 KB, block LDS 35840 B -> 4 blocks/CU, NO tail
// (grid = exactly 4 blocks/CU). Depth-2: 2 stages (4 loads) in flight,
// s_waitcnt vmcnt(2) per step, never drains in the steady loop.
__global__ __launch_bounds__(256, 4) void vq_main(const float* __restrict__ in,
        const float* __restrict__ emb,
        const _Float16* __restrict__ Ef,
        const float* __restrict__ me2h, float* __restrict__ out) {

    __shared__ char smem[35840];
    // phase 1: Xs[128][68] @ 0 (34816 B)
    // loop:    buf0/1/2 @ 0/8192/16384 (8 KB each); me2l @ 24576 (4 KB)
    // post:    idxs @ 0 (512 B), wsum @ 512, Q[128][68] @ 1024 (ends 35840)
    float (*Xs)[68] = (float (*)[68])smem;
    float (*Q)[68]  = (float (*)[68])(smem + 1024);
    int*   idxs = (int*)smem;
    float* wsum = (float*)(smem + 512);
    const char* me2l = (const char*)smem + 24576;

    const int tid  = threadIdx.x;
    const int lane = tid & 63;
    const int w    = tid >> 6;      // wave owns queries w*32 .. w*32+31
    const int ln   = lane & 15;
    const int lq   = lane >> 4;

    const int n0   = blockIdx.x * BN;
    const int bb   = n0 >> 14;
    const int thw0 = n0 & (THW - 1);
    const float* inb = in  + (size_t)bb * CDIM * THW + thw0;
    float*      outb = out + (size_t)bb * CDIM * THW + thw0;

    // ---- stage X tile ([n][c] transpose) ----
    {
        const int nl = tid & 127;
        const int hf = tid >> 7;
        #pragma unroll 8
        for (int r = 0; r < 32; ++r) {
            const int c = hf * 32 + r;
            Xs[nl][c] = inb[(size_t)c * THW + nl];
        }
    }
    __syncthreads();

    // ---- B fragments (fp16 hi/lo) + ||x||^2 in registers ----
    half8 Bh[2][2], Bl[2][2];
    float x2r[2];
    #pragma unroll
    for (int qg = 0; qg < 2; ++qg) {
        const int q = w * 32 + qg * 16 + ln;
        float s = 0.f;
        #pragma unroll
        for (int ch = 0; ch < 2; ++ch) {
            const float* xp = &Xs[q][ch * 32 + lq * 8];
            const float4 xa = *(const float4*)(xp);
            const float4 xb = *(const float4*)(xp + 4);
            const float xv[8] = {xa.x, xa.y, xa.z, xa.w, xb.x, xb.y, xb.z, xb.w};
            #pragma unroll
            for (int j = 0; j < 8; ++j) {
                const _Float16 h = (_Float16)xv[j];
                const _Float16 l = (_Float16)((xv[j] - (float)h) * 4096.0f);
                Bh[qg][ch][j] = h;
                Bl[qg][ch][j] = l;
                s = fmaf(xv[j], xv[j], s);
            }
        }
        s += __shfl_xor(s, 16, 64);     // fold the 4 lq-quads: full ||x||^2
        s += __shfl_xor(s, 32, 64);
        x2r[qg] = s;
    }
    __syncthreads();    // Xs dead -> smem[0..28K) becomes bufs + me2l

    // me2 -> LDS (4 KB, one 16B chunk per thread); retires with stage 0
    __builtin_amdgcn_global_load_lds(
        (const unsigned int*)((const char*)me2h + w * 1024 + lane * 16),
        (unsigned int*)(smem + 24576 + w * 1024), 16, 0, 0);

    const char* Efb = (const char*)Ef + (size_t)(w * 1024 + lane * 16);

    float bests[2] = {-3.4e38f, -3.4e38f};
    int   besti[2] = {0, 0};

#define STAGE(K, BI)                                                          \
    {   const char* gsrc = Efb + (size_t)(K) * 8192;                          \
        char* ldst = smem + (BI) * 8192 + w * 1024;                           \
        __builtin_amdgcn_global_load_lds((const unsigned int*)(gsrc),         \
                (unsigned int*)(ldst), 16, 0, 0);                             \
        __builtin_amdgcn_global_load_lds((const unsigned int*)(gsrc + 4096),  \
                (unsigned int*)(ldst + 4096), 16, 0, 0);                      \
    }

#define COMPUTE(S, BI)                                                        \
    {   const char* bufb = smem + (BI) * 8192;                                \
        __builtin_amdgcn_s_setprio(1);                                        \
        _Pragma("unroll")                                                     \
        for (int tt = 0; tt < 2; ++tt) {                                      \
            const half8* A = (const half8*)(bufb + tt * 4096);                \
            const half8 ah0 = A[lane];                                        \
            const half8 ah1 = A[64 + lane];                                   \
            const half8 al0 = A[128 + lane];                                  \
            const half8 al1 = A[192 + lane];                                  \
            const int kt = (S) * 2 + tt;                                      \
            const f32x4 e2v = *(const f32x4*)(me2l + kt * 64 + lq * 16);      \
            const int kb = kt * 16;                                           \
            _Pragma("unroll")                                                 \
            for (int qg = 0; qg < 2; ++qg) {                                  \
                f32x4 hh = e2v;                                               \
                hh = __builtin_amdgcn_mfma_f32_16x16x32_f16(ah0, Bh[qg][0], hh, 0, 0, 0); \
                hh = __builtin_amdgcn_mfma_f32_16x16x32_f16(ah1, Bh[qg][1], hh, 0, 0, 0); \
                f32x4 cr = {0.f, 0.f, 0.f, 0.f};                              \
                cr = __builtin_amdgcn_mfma_f32_16x16x32_f16(ah0, Bl[qg][0], cr, 0, 0, 0); \
                cr = __builtin_amdgcn_mfma_f32_16x16x32_f16(al0, Bh[qg][0], cr, 0, 0, 0); \
                cr = __builtin_amdgcn_mfma_f32_16x16x32_f16(ah1, Bl[qg][1], cr, 0, 0, 0); \
                cr = __builtin_amdgcn_mfma_f32_16x16x32_f16(al1, Bh[qg][1], cr, 0, 0, 0); \
                _Pragma("unroll")                                             \
                for (int r = 0; r < 4; ++r) {                                 \
                    const float cv = fmaf(2.44140625e-4f, cr[r], hh[r]);      \
                    if (cv > bests[qg]) { bests[qg] = cv; besti[qg] = kb + r; } \
                }                                                             \
            }                                                                 \
        }                                                                     \
        __builtin_amdgcn_s_setprio(0);                                        \
    }

#define WAIT2 asm volatile("s_waitcnt vmcnt(2)" ::: "memory")
#define WAIT0 asm volatile("s_waitcnt vmcnt(0)" ::: "memory")
#define BAR   __builtin_amdgcn_s_barrier()
#define STEP(S, CB, SB) { WAIT2; BAR; STAGE((S) + 2, SB) COMPUTE(S, CB) }

    // prologue: stage steps 0,1 (buffers 0,1); steady: wait own stage(s)
    // landed (vmcnt(2): stage(s+1) still in flight), barrier (all waves'
    // stage(s) landed AND buffer (s+2)%3 free), issue stage(s+2), compute.
    STAGE(0, 0)
    STAGE(1, 1)
    for (int s0 = 0; s0 < 30; s0 += 3) {
        STEP(s0,     0, 2)
        STEP(s0 + 1, 1, 0)
        STEP(s0 + 2, 2, 1)
    }
    WAIT2; BAR; COMPUTE(30, 0)
    WAIT0; BAR; COMPUTE(31, 1)

    __syncthreads();    // all waves done with bufs before idxs overwrite

    besti[0] += lq * 4;     // full code index = kt*16 + lq*4 + r
    besti[1] += lq * 4;

    // ---- wave-internal argmax reduce across the 4 row-quads ----
    #pragma unroll
    for (int qg = 0; qg < 2; ++qg) {
        #pragma unroll
        for (int msk = 16; msk <= 32; msk <<= 1) {
            const float ov = __shfl_xor(bests[qg], msk, 64);
            const int   oi = __shfl_xor(besti[qg], msk, 64);
            if (ov > bests[qg] || (ov == bests[qg] && oi < besti[qg])) {
                bests[qg] = ov; besti[qg] = oi;
            }
        }
    }
    float lsum = 0.f;
    if (lq == 0) {
        #pragma unroll
        for (int qg = 0; qg < 2; ++qg) {
            const int q = w * 32 + qg * 16 + ln;
            idxs[q] = besti[qg];
            out[IDX_OFF + n0 + q] = (float)besti[qg];
            // d = -2*s ; loss term = d + ||x||^2
            lsum += fmaf(-2.0f, bests[qg], x2r[qg]);
        }
    }
    #pragma unroll
    for (int off = 32; off > 0; off >>= 1) lsum += __shfl_down(lsum, off, 64);
    if (lane == 0) wsum[w] = lsum;
    __syncthreads();
    if (tid == 0) {
        const float s = wsum[0] + wsum[1] + wsum[2] + wsum[3];
        atomicAdd(&out[LOSS_OFF],     s * (1.0f  / (float)QELEMS));
        atomicAdd(&out[LOSS_OFF + 1], s * (0.25f / (float)QELEMS));
    }

    // ---- epilogue: gather code rows into LDS, transpose-write ----
    {
        const int q  = tid >> 1;
        const int hf = tid & 1;
        const float* er = emb + (size_t)idxs[q] * CDIM + hf * 32;
        #pragma unroll
        for (int j = 0; j < 8; ++j) {
            const float4 v = *(const float4*)(er + 4 * j);
            *(float4*)(&Q[q][hf * 32 + 4 * j]) = v;
        }
    }
    __syncthreads();
    {
        const int nl = tid & 127;
        const int cb = tid >> 7;
        #pragma unroll 8
        for (int r = 0; r < 32; ++r) {
            const int c = 2 * r + cb;
            outb[(size_t)c * THW + nl] = Q[nl][c];
        }
    }
#undef STAGE
#undef COMPUTE
#undef WAIT2
#undef WAIT0
#undef BAR
#undef STEP
}

extern "C" void kernel_launch(void* const* d_in, const int* in_sizes, int n_in,
                              void* d_out, int out_size, void* d_ws, size_t ws_size,
                              hipStream_t stream) {
    const float* in  = (const float*)d_in[0];   // (8, 64, 16, 32, 32) fp32
    const float* emb = (const float*)d_in[1];   // (1024, 64) fp32
    float* out = (float*)d_out;
    _Float16* Ef   = (_Float16*)d_ws;                       // 64 tiles * 4 KB = 256 KB
    float*    me2h = (float*)((char*)d_ws + 262144);        // 1024 floats = -0.5*||e||^2

    vq_prep<<<KDIM / 16, 256, 0, stream>>>(emb, Ef, me2h, out);
    vq_main<<<NTOT / BN, 256, 0, stream>>>(in, emb, Ef, me2h, out);
}

// Round 6
// 133.670 us; speedup vs baseline: 1.0284x; 1.0284x over previous
//
#include <hip/hip_runtime.h>
#include <hip/hip_fp16.h>

// Problem: inputs (8, 64, 16, 32, 32) fp32, embedding (1024, 64) fp32
#define THW    16384
#define NTOT   131072
#define KDIM   1024
#define CDIM   64
#define QELEMS 8388608          // 8*64*16*32*32
#define LOSS_OFF 8388608
#define IDX_OFF  8388610
#define BN     128              // queries per block

typedef _Float16 half8   __attribute__((ext_vector_type(8)));
typedef _Float16 half4_t __attribute__((ext_vector_type(4)));
typedef float    f32x4   __attribute__((ext_vector_type(4)));

// ---- prep: zero losses; split E into fp16 hi/lo (lo scaled 2^12) into ONE
// interleaved buffer Ef[tile][slot][lane][8], slots = {h.ch0, h.ch1, l.ch0,
// l.ch1}; tile = 4 KB, linear in the exact lane order vq_main's ds_reads use,
// so global_load_lds (wave-uniform base + lane*16) can stage it untouched.
// me2h[row] = -0.5*||e||^2 (seeds the hh MFMA chain directly).
__global__ __launch_bounds__(256) void vq_prep(const float* __restrict__ emb,
        _Float16* __restrict__ Ef, float* __restrict__ me2h,
        float* __restrict__ out) {
    const int t = threadIdx.x;
    if (blockIdx.x == 0 && t == 0) { out[LOSS_OFF] = 0.f; out[LOSS_OFF + 1] = 0.f; }
    const int ln   = t >> 4;
    const int g    = t & 15;
    const int tile = blockIdx.x;
    const int row  = tile * 16 + ln;
    const int c0   = g * 4;
    float4 v = *(const float4*)(emb + (size_t)row * CDIM + c0);
    const float xs[4] = {v.x, v.y, v.z, v.w};
    half4_t h, l;
    float s = 0.f;
    #pragma unroll
    for (int j = 0; j < 4; ++j) {
        const _Float16 hj = (_Float16)xs[j];
        const _Float16 lj = (_Float16)((xs[j] - (float)hj) * 4096.0f);
        h[j] = hj; l[j] = lj;
        s = fmaf(xs[j], xs[j], s);
    }
    const int ch = c0 >> 5;
    const int lq = (c0 & 31) >> 3;
    const int j0 = c0 & 7;
    const int fl = lq * 16 + ln;
    *(half4_t*)(Ef + (((size_t)tile * 4 + ch)     * 64 + fl) * 8 + j0) = h;
    *(half4_t*)(Ef + (((size_t)tile * 4 + 2 + ch) * 64 + fl) * 8 + j0) = l;
    #pragma unroll
    for (int off = 1; off < 16; off <<= 1) s += __shfl_xor(s, off, 64);
    if (g == 0) me2h[row] = -0.5f * s;
}

// ---- main: 2x2 wave split (wq: query half, wk: tile parity).
// Each wave: 4 qg x 32 tiles -> A ds_read traffic halves per CU, and the
// MFMA:ds_read ratio doubles (24 MFMA per 4 ds_read_b128). Counted-vmcnt
// 3-buffer pipeline with 8 KB stages, 4 blocks/CU, no tail.
__global__ __launch_bounds__(256, 4) void vq_main(const float* __restrict__ in,
        const float* __restrict__ emb,
        const _Float16* __restrict__ Ef,
        const float* __restrict__ me2h, float* __restrict__ out) {

    __shared__ char smem[35840];
    // phase 1: Xs[128][68] @ 0 (34816 B)
    // loop:    buf0/1/2 @ 0/8192/16384 (8 KB each); me2l @ 24576 (4 KB)
    //          free 28672..35840 (combine arrays live here)
    // post:    bv @ 28672 (512 B), bj @ 29184 (512 B),
    //          idxs @ 34816 (512 B), wsum @ 35328, Q[128][68] @ 0 (gather)
    float (*Xs)[68] = (float (*)[68])smem;
    float (*Q)[68]  = (float (*)[68])smem;
    float* bv   = (float*)(smem + 28672);
    int*   bj   = (int*)(smem + 29184);
    int*   idxs = (int*)(smem + 34816);
    float* wsum = (float*)(smem + 35328);
    const char* me2l = (const char*)smem + 24576;

    const int tid  = threadIdx.x;
    const int lane = tid & 63;
    const int w    = tid >> 6;
    const int wk   = w & 1;         // tile parity this wave computes
    const int wq   = w >> 1;        // query half this wave computes
    const int ln   = lane & 15;
    const int lq   = lane >> 4;

    const int n0   = blockIdx.x * BN;
    const int bb   = n0 >> 14;
    const int thw0 = n0 & (THW - 1);
    const float* inb = in  + (size_t)bb * CDIM * THW + thw0;
    float*      outb = out + (size_t)bb * CDIM * THW + thw0;

    // ---- stage X tile ([n][c] transpose) ----
    {
        const int nl = tid & 127;
        const int hf = tid >> 7;
        #pragma unroll 8
        for (int r = 0; r < 32; ++r) {
            const int c = hf * 32 + r;
            Xs[nl][c] = inb[(size_t)c * THW + nl];
        }
    }
    __syncthreads();

    // ---- B fragments (fp16 hi/lo) + ||x||^2 in registers: 4 qg groups ----
    half8 Bh[4][2], Bl[4][2];
    float x2r[4];
    #pragma unroll
    for (int qg = 0; qg < 4; ++qg) {
        const int q = wq * 64 + qg * 16 + ln;
        float s = 0.f;
        #pragma unroll
        for (int ch = 0; ch < 2; ++ch) {
            const float* xp = &Xs[q][ch * 32 + lq * 8];
            const float4 xa = *(const float4*)(xp);
            const float4 xb = *(const float4*)(xp + 4);
            const float xv[8] = {xa.x, xa.y, xa.z, xa.w, xb.x, xb.y, xb.z, xb.w};
            #pragma unroll
            for (int j = 0; j < 8; ++j) {
                const _Float16 h = (_Float16)xv[j];
                const _Float16 l = (_Float16)((xv[j] - (float)h) * 4096.0f);
                Bh[qg][ch][j] = h;
                Bl[qg][ch][j] = l;
                s = fmaf(xv[j], xv[j], s);
            }
        }
        s += __shfl_xor(s, 16, 64);     // fold the 4 lq-quads: full ||x||^2
        s += __shfl_xor(s, 32, 64);
        x2r[qg] = s;
    }
    __syncthreads();    // Xs dead -> smem[0..28K) becomes bufs + me2l

    // me2 -> LDS (4 KB, one 16B chunk per thread); retires with stage 0
    __builtin_amdgcn_global_load_lds(
        (const unsigned int*)((const char*)me2h + w * 1024 + lane * 16),
        (unsigned int*)(smem + 24576 + w * 1024), 16, 0, 0);

    const char* Efb = (const char*)Ef + (size_t)(w * 1024 + lane * 16);

    float bests[4] = {-3.4e38f, -3.4e38f, -3.4e38f, -3.4e38f};
    int   besti[4] = {0, 0, 0, 0};

#define STAGE(K, BI)                                                          \
    {   const char* gsrc = Efb + (size_t)(K) * 8192;                          \
        char* ldst = smem + (BI) * 8192 + w * 1024;                           \
        __builtin_amdgcn_global_load_lds((const unsigned int*)(gsrc),         \
                (unsigned int*)(ldst), 16, 0, 0);                             \
        __builtin_amdgcn_global_load_lds((const unsigned int*)(gsrc + 4096),  \
                (unsigned int*)(ldst + 4096), 16, 0, 0);                      \
    }

// each wave computes only the tile of its parity: kt = S*2 + wk
#define COMPUTE(S, BI)                                                        \
    {   const half8* A = (const half8*)(smem + (BI) * 8192 + wk * 4096);      \
        const half8 ah0 = A[lane];                                            \
        const half8 ah1 = A[64 + lane];                                       \
        const half8 al0 = A[128 + lane];                                      \
        const half8 al1 = A[192 + lane];                                      \
        const int kt = (S) * 2 + wk;                                          \
        const f32x4 e2v = *(const f32x4*)(me2l + kt * 64 + lq * 16);          \
        const int kb = kt * 16;                                               \
        __builtin_amdgcn_s_setprio(1);                                        \
        _Pragma("unroll")                                                     \
        for (int qg = 0; qg < 4; ++qg) {                                      \
            f32x4 hh = e2v;                                                   \
            hh = __builtin_amdgcn_mfma_f32_16x16x32_f16(ah0, Bh[qg][0], hh, 0, 0, 0); \
            hh = __builtin_amdgcn_mfma_f32_16x16x32_f16(ah1, Bh[qg][1], hh, 0, 0, 0); \
            f32x4 cr = {0.f, 0.f, 0.f, 0.f};                                  \
            cr = __builtin_amdgcn_mfma_f32_16x16x32_f16(ah0, Bl[qg][0], cr, 0, 0, 0); \
            cr = __builtin_amdgcn_mfma_f32_16x16x32_f16(al0, Bh[qg][0], cr, 0, 0, 0); \
            cr = __builtin_amdgcn_mfma_f32_16x16x32_f16(ah1, Bl[qg][1], cr, 0, 0, 0); \
            cr = __builtin_amdgcn_mfma_f32_16x16x32_f16(al1, Bh[qg][1], cr, 0, 0, 0); \
            _Pragma("unroll")                                                 \
            for (int r = 0; r < 4; ++r) {                                     \
                const float cv = fmaf(2.44140625e-4f, cr[r], hh[r]);          \
                if (cv > bests[qg]) { bests[qg] = cv; besti[qg] = kb + r; }    \
            }                                                                 \
        }                                                                     \
        __builtin_amdgcn_s_setprio(0);                                        \
    }

#define WAIT2 asm volatile("s_waitcnt vmcnt(2)" ::: "memory")
#define WAIT0 asm volatile("s_waitcnt vmcnt(0)" ::: "memory")
#define BAR   __builtin_amdgcn_s_barrier()
#define STEP(S, CB, SB) { WAIT2; BAR; STAGE((S) + 2, SB) COMPUTE(S, CB) }

    // prologue: stage steps 0,1 (buffers 0,1); steady: wait own stage(s)
    // landed (vmcnt(2): stage(s+1) still in flight), barrier (all waves'
    // stage(s) landed AND buffer (s+2)%3 free), issue stage(s+2), compute.
    STAGE(0, 0)
    STAGE(1, 1)
    for (int s0 = 0; s0 < 30; s0 += 3) {
        STEP(s0,     0, 2)
        STEP(s0 + 1, 1, 0)
        STEP(s0 + 2, 2, 1)
    }
    WAIT2; BAR; COMPUTE(30, 0)
    WAIT0; BAR; COMPUTE(31, 1)

    besti[0] += lq * 4;     // full code index = kt*16 + lq*4 + r
    besti[1] += lq * 4;
    besti[2] += lq * 4;
    besti[3] += lq * 4;

    // ---- wave-internal argmax reduce across the 4 row-quads ----
    #pragma unroll
    for (int qg = 0; qg < 4; ++qg) {
        #pragma unroll
        for (int msk = 16; msk <= 32; msk <<= 1) {
            const float ov = __shfl_xor(bests[qg], msk, 64);
            const int   oi = __shfl_xor(besti[qg], msk, 64);
            if (ov > bests[qg] || (ov == bests[qg] && oi < besti[qg])) {
                bests[qg] = ov; besti[qg] = oi;
            }
        }
    }

    // ---- cross-wave combine: wk=1 publishes, wk=0 merges (x2 in regs) ----
    if (wk == 1 && lq == 0) {
        #pragma unroll
        for (int qg = 0; qg < 4; ++qg) {
            const int q = wq * 64 + qg * 16 + ln;
            bv[q] = bests[qg];
            bj[q] = besti[qg];
        }
    }
    __syncthreads();    // bv/bj visible; all waves done reading bufs

    float lsum = 0.f;
    if (wk == 0 && lq == 0) {
        #pragma unroll
        for (int qg = 0; qg < 4; ++qg) {
            const int q = wq * 64 + qg * 16 + ln;
            const float ov = bv[q];
            const int   oi = bj[q];
            if (ov > bests[qg] || (ov == bests[qg] && oi < besti[qg])) {
                bests[qg] = ov; besti[qg] = oi;
            }
            idxs[q] = besti[qg];
            out[IDX_OFF + n0 + q] = (float)besti[qg];
            // d = -2*s ; loss term = d + ||x||^2
            lsum += fmaf(-2.0f, bests[qg], x2r[qg]);
        }
    }
    #pragma unroll
    for (int off = 32; off > 0; off >>= 1) lsum += __shfl_down(lsum, off, 64);
    if (lane == 0) wsum[w] = lsum;
    __syncthreads();    // idxs + wsum visible
    if (tid == 0) {
        const float s = wsum[0] + wsum[1] + wsum[2] + wsum[3];
        atomicAdd(&out[LOSS_OFF],     s * (1.0f  / (float)QELEMS));
        atomicAdd(&out[LOSS_OFF + 1], s * (0.25f / (float)QELEMS));
    }

    // ---- epilogue: gather code rows into LDS (Q aliases dead bufs), transpose-write ----
    {
        const int q  = tid >> 1;
        const int hf = tid & 1;
        const float* er = emb + (size_t)idxs[q] * CDIM + hf * 32;
        #pragma unroll
        for (int j = 0; j < 8; ++j) {
            const float4 v = *(const float4*)(er + 4 * j);
            *(float4*)(&Q[q][hf * 32 + 4 * j]) = v;
        }
    }
    __syncthreads();
    {
        const int nl = tid & 127;
        const int cb = tid >> 7;
        #pragma unroll 8
        for (int r = 0; r < 32; ++r) {
            const int c = 2 * r + cb;
            outb[(size_t)c * THW + nl] = Q[nl][c];
        }
    }
#undef STAGE
#undef COMPUTE
#undef WAIT2
#undef WAIT0
#undef BAR
#undef STEP
}

extern "C" void kernel_launch(void* const* d_in, const int* in_sizes, int n_in,
                              void* d_out, int out_size, void* d_ws, size_t ws_size,
                              hipStream_t stream) {
    const float* in  = (const float*)d_in[0];   // (8, 64, 16, 32, 32) fp32
    const float* emb = (const float*)d_in[1];   // (1024, 64) fp32
    float* out = (float*)d_out;
    _Float16* Ef   = (_Float16*)d_ws;                       // 64 tiles * 4 KB = 256 KB
    float*    me2h = (float*)((char*)d_ws + 262144);        // 1024 floats = -0.5*||e||^2

    vq_prep<<<KDIM / 16, 256, 0, stream>>>(emb, Ef, me2h, out);
    vq_main<<<NTOT / BN, 256, 0, stream>>>(in, emb, Ef, me2h, out);
}